// Round 3
// baseline (400.716 us; speedup 1.0000x reference)
//
#include <hip/hip_runtime.h>

typedef unsigned short u16;
typedef __attribute__((ext_vector_type(8))) short short8;
typedef __attribute__((ext_vector_type(4))) float f32x4;

#define MFMA16(a, b, c) __builtin_amdgcn_mfma_f32_16x16x32_bf16((a), (b), (c), 0, 0, 0)
#define WAITV(N) asm volatile("s_waitcnt vmcnt(" #N ")" ::: "memory")
#define BARS() __builtin_amdgcn_s_barrier()
#define MFENCE() asm volatile("" ::: "memory")

__device__ __forceinline__ u16 f2b(float f) {
  unsigned b = __float_as_uint(f);
  b += 0x7FFFu + ((b >> 16) & 1u);
  return (u16)(b >> 16);
}

__device__ __forceinline__ void gload_lds16(const void* g, void* l) {
  __builtin_amdgcn_global_load_lds((const __attribute__((address_space(1))) void*)g,
                                   (__attribute__((address_space(3))) void*)l, 16, 0, 0);
}

// fast exact-enough GELU: erf via Abramowitz-Stegun 7.1.26 (|err|<=1.5e-7)
__device__ __forceinline__ float fast_gelu(float x) {
  const float u = x * 0.70710678118654752f;
  const float au = fabsf(u);
  float d = 1.f + 0.3275911f * au;
  float tt;
  asm("v_rcp_f32 %0, %1" : "=v"(tt) : "v"(d));
  float p = 1.061405429f * tt - 1.453152027f;
  p = p * tt + 1.421413741f;
  p = p * tt - 0.284496736f;
  p = p * tt + 0.254829592f;
  p = p * tt;
  const float e = __expf(-u * u);
  const float erf_au = 1.f - p * e;
  return 0.5f * x * (1.f + copysignf(erf_au, x));
}

// ---------------- small setup kernels ----------------
__global__ __launch_bounds__(256) void f2bf_kernel(const float* __restrict__ s,
                                                   u16* __restrict__ d, int n) {
  int i = blockIdx.x * 256 + threadIdx.x;
  if (i < n) d[i] = f2b(s[i]);
}

__global__ __launch_bounds__(256) void biasfull_kernel(const float* __restrict__ tbl,
                                                       const int* __restrict__ ridx,
                                                       float* __restrict__ o) {
  int i = blockIdx.x * 256 + threadIdx.x;
  int hm = i >> 12, nm = i & 4095;
  o[i] = tbl[ridx[nm] * 8 + hm];
}

// ---------------- K1: LN1 + window partition -> Y bf16 [65536][256] ----------------
__global__ __launch_bounds__(256) void ln1_win_kernel(const float* __restrict__ x,
                                                      const float* __restrict__ g,
                                                      const float* __restrict__ b,
                                                      u16* __restrict__ y) {
  __shared__ float red[2][4][64];
  const int bh = blockIdx.x;  // b*64 + h
  const int bb = bh >> 6, h = bh & 63;
  const int w = threadIdx.x & 63, cg = threadIdx.x >> 6;
  const float* xp = x + (size_t)bb * 1048576 + (size_t)h * 64 + w;
  float vals[64];
  float s = 0.f, ss = 0.f;
#pragma unroll
  for (int j = 0; j < 64; ++j) {
    float v = xp[(size_t)(cg * 64 + j) * 4096];
    vals[j] = v;
    s += v;
    ss += v * v;
  }
  red[0][cg][w] = s;
  red[1][cg][w] = ss;
  __syncthreads();
  const float S = red[0][0][w] + red[0][1][w] + red[0][2][w] + red[0][3][w];
  const float Q = red[1][0][w] + red[1][1][w] + red[1][2][w] + red[1][3][w];
  const float m = S * (1.f / 256.f);
  const float rstd = rsqrtf(Q * (1.f / 256.f) - m * m + 1e-5f);
  const int win = bb * 64 + ((h >> 3) << 3) + (w >> 3);
  const int tok = ((h & 7) << 3) + (w & 7);
  u16* yp = y + (size_t)win * 16384 + tok * 256 + cg * 64;
#pragma unroll
  for (int jj = 0; jj < 8; ++jj) {
    short8 o;
#pragma unroll
    for (int q = 0; q < 8; ++q) {
      const int c64 = jj * 8 + q;
      const int c = cg * 64 + c64;
      o[q] = (short)f2b((vals[c64] - m) * rstd * g[c] + b[c]);
    }
    *(short8*)&yp[jj * 8] = o;
  }
}

// ======================= persistent GEMM, K=256, B-in-registers =======================
// Block: 256 thr (4 waves), output 128(M) x 64(N) per m-tile, CHUNK m-tiles per block.
// W-slice [64][256] staged once -> LDS -> 16 reg fragments (64 VGPR). A streams through
// 3 LDS regions (16KB each, 48KB total -> 3 blocks/CU) as chunks of [128 rows][64 k].
// Schedule per chunk c: wait vmcnt(exact) ; s_barrier ; compute(c) ; s_barrier ;
// stage(c+3 -> same region). Epilogue per m-tile after kc3's stage.
// Exact wait literals (in-order vmcnt FIFO, 4 loads/stage, EV = epilogue vmem ops):
//   m=0: 8,8,8,8   (no stores in window yet)
//   1<=m<=CHUNK-2: 8+EV, 8+EV, 8+EV, 8
//   m=CHUNK-1: 8+EV, 8+EV, 4+EV, 0
// EV: EPI0 (qkv scatter) = 32 ; EPI1 (proj+residual) = 40 ; EPI2 (fc1 gelu) = 32.
// Under-count impossible (extra unexpected ops only tighten waits); bias loads are
// loop-invariant (hoisted; if not, waits over-wait — still safe).
template <int EPI, int NNT, int CHUNK, int NCOLS>
__global__ __launch_bounds__(256, 3) void gemm_pers(const u16* __restrict__ A,
                                                    const u16* __restrict__ W,
                                                    const float* __restrict__ bias,
                                                    u16* __restrict__ outh,
                                                    float* __restrict__ outf,
                                                    const float* __restrict__ aux) {
  __shared__ __align__(16) u16 As[3 * 8192];
  const int bid = blockIdx.x;
  const int nt = bid % NNT, mg = bid / NNT;
  const int tid = threadIdx.x;
  const int wv = tid >> 6, lane = tid & 63;
  const int wr = (wv >> 1) << 6;  // wave row half (0/64)
  const int wc = (wv & 1) << 5;   // wave col half (0/32)
  const int lrow = lane >> 3;
  const int lkswz = (((lane & 7) ^ lrow) << 3);
  const int lr = lane & 15, lg = lane >> 4;
  const int swz = (lr & 7) << 3;
  const u16* Wb = W + (size_t)nt * 64 * 256;

  // ---- stage B slice [64][256] into regions 0..1 (source pre-swizzled per row) ----
  {
    const int srh = lane >> 5;            // 0/1: which of the 2 rows this lane covers
    const int klin = (lane & 31) << 3;    // 0..248
#pragma unroll
    for (int i = 0; i < 8; ++i) {
      const int rb2 = (i * 4 + wv) * 2;
      const int srow = rb2 + srh;
      gload_lds16(Wb + (size_t)srow * 256 + (klin ^ ((srow & 7) << 3)), &As[rb2 * 256]);
    }
  }
  const int mt0 = mg * CHUNK * 128;
#define STAGEA(MR, KC, RG)                                                              \
  {                                                                                     \
    _Pragma("unroll") for (int i_ = 0; i_ < 4; ++i_) {                                  \
      const int rb_ = wv * 32 + i_ * 8;                                                 \
      gload_lds16(A + (size_t)((MR) + rb_ + lrow) * 256 + (KC) * 64 + lkswz,            \
                  &As[(RG)*8192 + rb_ * 64]);                                           \
    }                                                                                   \
  }
  STAGEA(mt0, 0, 2);
  WAITV(4);  // B's 8 calls done; A0's 4 in flight
  BARS();
  MFENCE();
  short8 breg[2][8];
#pragma unroll
  for (int ni = 0; ni < 2; ++ni)
#pragma unroll
    for (int s = 0; s < 8; ++s)
      breg[ni][s] = *(const short8*)&As[(wc + ni * 16 + lr) * 256 + ((s * 32 + lg * 8) ^ swz)];
  asm volatile("s_waitcnt lgkmcnt(0)" ::: "memory");  // B reads in regs before overwrite
  BARS();
  STAGEA(mt0, 1, 0);
  STAGEA(mt0, 2, 1);

  f32x4 acc[4][2];
#pragma unroll
  for (int mi = 0; mi < 4; ++mi)
#pragma unroll
    for (int ni = 0; ni < 2; ++ni) acc[mi][ni] = (f32x4){0.f, 0.f, 0.f, 0.f};

#define COMPUTE(RG, KC)                                                                 \
  {                                                                                     \
    const u16* Ar = &As[(RG)*8192];                                                     \
    _Pragma("unroll") for (int kk = 0; kk < 2; ++kk) {                                  \
      const int kq = (kk * 32 + lg * 8) ^ swz;                                          \
      short8 af[4];                                                                     \
      _Pragma("unroll") for (int mi = 0; mi < 4; ++mi)                                  \
          af[mi] = *(const short8*)&Ar[(wr + mi * 16 + lr) * 64 + kq];                  \
      _Pragma("unroll") for (int mi = 0; mi < 4; ++mi)                                  \
          _Pragma("unroll") for (int ni = 0; ni < 2; ++ni)                              \
              acc[mi][ni] = MFMA16(af[mi], breg[ni][(KC)*2 + kk], acc[mi][ni]);         \
    }                                                                                   \
  }

  auto EPILOG = [&](int mrow0) {
#pragma unroll
    for (int ni = 0; ni < 2; ++ni) {
      const int col = nt * 64 + wc + ni * 16 + lr;
      const float bv = bias[col];
      if constexpr (EPI == 0) {
        const int which = col >> 8, cc = col & 255;
        u16* dst = outh + (size_t)which * 16777216ull + (cc & 31) + ((cc >> 5) << 11);
        const float scl = (which == 0) ? 0.17677669529663689f : 1.0f;
#pragma unroll
        for (int mi = 0; mi < 4; ++mi)
#pragma unroll
          for (int r = 0; r < 4; ++r) {
            const int row = mrow0 + wr + mi * 16 + lg * 4 + r;
            const int win = row >> 6, tk = row & 63;
            dst[(size_t)win * 16384 + (tk << 5)] = f2b((acc[mi][ni][r] + bv) * scl);
          }
      } else if constexpr (EPI == 1) {
#pragma unroll
        for (int mi = 0; mi < 4; ++mi) {
          const int row0 = mrow0 + wr + mi * 16 + lg * 4;
          const int win = row0 >> 6, tk = row0 & 63;
          const int bb = win >> 6;
          const int h = (((win >> 3) & 7) << 3) + (tk >> 3);
          const int w0 = ((win & 7) << 3) + (tk & 7);
          const f32x4 xv = *(const f32x4*)&aux[(((size_t)bb * 256 + col) * 64 + h) * 64 + w0];
#pragma unroll
          for (int r = 0; r < 4; ++r)
            outf[(size_t)(row0 + r) * 256 + col] = acc[mi][ni][r] + bv + xv[r];
        }
      } else {  // EPI == 2 : fc1 + gelu
#pragma unroll
        for (int mi = 0; mi < 4; ++mi)
#pragma unroll
          for (int r = 0; r < 4; ++r) {
            const int row = mrow0 + wr + mi * 16 + lg * 4 + r;
            outh[(size_t)row * NCOLS + col] = f2b(fast_gelu(acc[mi][ni][r] + bv));
          }
      }
    }
#pragma unroll
    for (int mi = 0; mi < 4; ++mi)
#pragma unroll
      for (int ni = 0; ni < 2; ++ni) acc[mi][ni] = (f32x4){0.f, 0.f, 0.f, 0.f};
  };

#define WAITV_EPI()                                  \
  if constexpr (EPI == 1) WAITV(48); else WAITV(40)
#define WAITV_TL2()                                  \
  if constexpr (EPI == 1) WAITV(44); else WAITV(36)

  // ---- m = 0 (no stores in FIFO window yet) ----
  WAITV(8); BARS(); MFENCE(); COMPUTE(2, 0); BARS(); STAGEA(mt0, 3, 2);
  WAITV(8); BARS(); MFENCE(); COMPUTE(0, 1); BARS(); STAGEA(mt0 + 128, 0, 0);
  WAITV(8); BARS(); MFENCE(); COMPUTE(1, 2); BARS(); STAGEA(mt0 + 128, 1, 1);
  WAITV(8); BARS(); MFENCE(); COMPUTE(2, 3); BARS(); STAGEA(mt0 + 128, 2, 2);
  EPILOG(mt0);
  // ---- middle m-tiles ----
  int rr = 0;  // region of chunk (m=1, kc=0)
  for (int m = 1; m < CHUNK - 1; ++m) {
    const int mr = mt0 + m * 128;
    WAITV_EPI(); BARS(); MFENCE(); COMPUTE(rr, 0); BARS(); STAGEA(mr, 3, rr);
    rr = (rr == 2) ? 0 : rr + 1;
    WAITV_EPI(); BARS(); MFENCE(); COMPUTE(rr, 1); BARS(); STAGEA(mr + 128, 0, rr);
    rr = (rr == 2) ? 0 : rr + 1;
    WAITV_EPI(); BARS(); MFENCE(); COMPUTE(rr, 2); BARS(); STAGEA(mr + 128, 1, rr);
    rr = (rr == 2) ? 0 : rr + 1;
    WAITV(8);   BARS(); MFENCE(); COMPUTE(rr, 3); BARS(); STAGEA(mr + 128, 2, rr);
    rr = (rr == 2) ? 0 : rr + 1;
    EPILOG(mr);
  }
  // ---- last m-tile ----
  {
    const int mr = mt0 + (CHUNK - 1) * 128;
    WAITV_EPI(); BARS(); MFENCE(); COMPUTE(rr, 0); BARS(); STAGEA(mr, 3, rr);
    rr = (rr == 2) ? 0 : rr + 1;
    WAITV_EPI(); BARS(); MFENCE(); COMPUTE(rr, 1); BARS();
    rr = (rr == 2) ? 0 : rr + 1;
    WAITV_TL2(); BARS(); MFENCE(); COMPUTE(rr, 2); BARS();
    rr = (rr == 2) ? 0 : rr + 1;
    WAITV(0);    BARS(); MFENCE(); COMPUTE(rr, 3);
    EPILOG(mr);
  }
#undef STAGEA
#undef COMPUTE
#undef WAITV_EPI
#undef WAITV_TL2
}

// ======================= fc2: streaming GEMM, counted-vmcnt 2-buf =======================
// out = A[M x 1024] * W[256 x 1024]^T + bias + aux residual -> d_out BCHW fp32
__global__ __launch_bounds__(256) void gemm_fc2(const u16* __restrict__ A,
                                                const u16* __restrict__ W,
                                                const float* __restrict__ bias,
                                                float* __restrict__ outf,
                                                const float* __restrict__ aux) {
  __shared__ __align__(16) u16 As[2][128 * 64];
  __shared__ __align__(16) u16 Bs[2][128 * 64];
  const int K = 1024;
  const int mt = blockIdx.x >> 1;
  const int nt = blockIdx.x & 1;
  const int tid = threadIdx.x;
  const int wv = tid >> 6, lane = tid & 63;
  const int wr = (wv >> 1) << 6;
  const int wc = (wv & 1) << 6;
  const int lrow = lane >> 3;
  const int lkswz = (((lane & 7) ^ lrow) << 3);
  const int lr = lane & 15, lg = lane >> 4;
  const int swz = (lr & 7) << 3;
  f32x4 acc[4][4];
#pragma unroll
  for (int mi = 0; mi < 4; ++mi)
#pragma unroll
    for (int ni = 0; ni < 4; ++ni) acc[mi][ni] = (f32x4){0.f, 0.f, 0.f, 0.f};
  const u16* Ab = A + (size_t)mt * 128 * K;
  const u16* Wb = W + (size_t)nt * 128 * K;

#define STG(BF, T)                                                                      \
  {                                                                                     \
    const int kt_ = (T) << 6;                                                           \
    _Pragma("unroll") for (int i_ = 0; i_ < 4; ++i_) {                                  \
      const int rb_ = wv * 32 + i_ * 8;                                                 \
      gload_lds16(Ab + (size_t)(rb_ + lrow) * K + kt_ + lkswz, &As[BF][rb_ * 64]);      \
    }                                                                                   \
    _Pragma("unroll") for (int i_ = 0; i_ < 4; ++i_) {                                  \
      const int rb_ = wv * 32 + i_ * 8;                                                 \
      gload_lds16(Wb + (size_t)(rb_ + lrow) * K + kt_ + lkswz, &Bs[BF][rb_ * 64]);      \
    }                                                                                   \
  }
#define CMP(BF)                                                                         \
  {                                                                                     \
    _Pragma("unroll") for (int kk = 0; kk < 2; ++kk) {                                  \
      const int kq = (kk * 32 + lg * 8) ^ swz;                                          \
      short8 a_[4], b_[4];                                                              \
      _Pragma("unroll") for (int mi = 0; mi < 4; ++mi)                                  \
          a_[mi] = *(const short8*)&As[BF][(wr + mi * 16 + lr) * 64 + kq];              \
      _Pragma("unroll") for (int ni = 0; ni < 4; ++ni)                                  \
          b_[ni] = *(const short8*)&Bs[BF][(wc + ni * 16 + lr) * 64 + kq];              \
      _Pragma("unroll") for (int mi = 0; mi < 4; ++mi)                                  \
          _Pragma("unroll") for (int ni = 0; ni < 4; ++ni)                              \
              acc[mi][ni] = MFMA16(a_[mi], b_[ni], acc[mi][ni]);                        \
    }                                                                                   \
  }
  STG(0, 0);
  STG(1, 1);
  for (int t = 0; t < 15; ++t) {
    WAITV(8);  // tile t's 8 calls done; t+1's 8 in flight
    BARS();
    MFENCE();
    CMP(t & 1);
    BARS();
    if (t + 2 < 16) STG(t & 1, t + 2);
  }
  WAITV(0);
  BARS();
  MFENCE();
  CMP(1);
#undef STG
#undef CMP
  const int row0 = mt * 128 + wr + lg * 4;
  const int col0 = nt * 128 + wc + lr;
#pragma unroll
  for (int mi = 0; mi < 4; ++mi)
#pragma unroll
    for (int ni = 0; ni < 4; ++ni) {
      const int col = col0 + ni * 16;
      const float bv = bias[col];
      const int row = row0 + mi * 16;
      const int win = row >> 6, tk = row & 63;
      const int bb = win >> 6;
      const int h = (((win >> 3) & 7) << 3) + (tk >> 3);
      const int w = ((win & 7) << 3) + (tk & 7);
      f32x4 v;
#pragma unroll
      for (int r = 0; r < 4; ++r)
        v[r] = acc[mi][ni][r] + bv + aux[(size_t)(row + r) * 256 + col];
      *(f32x4*)&outf[(((size_t)bb * 256 + col) * 64 + h) * 64 + w] = v;
    }
}

// ---------------- K3: windowed attention, 1 wave per (window, head) ----------------
__global__ __launch_bounds__(64) void attn_kernel(const u16* __restrict__ qkv,
                                                  const float* __restrict__ biasf,
                                                  u16* __restrict__ aout) {
  __shared__ __align__(16) u16 qs[64 * 40];
  __shared__ __align__(16) u16 ks[64 * 40];
  __shared__ __align__(16) u16 vt[32 * 72];
  __shared__ __align__(16) u16 pp[64 * 72];
  const int wh = blockIdx.x;
  const int head = wh & 7;
  const int win = wh >> 3;
  const int lane = threadIdx.x;
  const int lr = lane & 15, lg = lane >> 4;
  const u16* qg = qkv + (size_t)wh * 2048;
  const u16* kg = qkv + 16777216ull + (size_t)wh * 2048;
  const u16* vg = qkv + 33554432ull + (size_t)wh * 2048;
#pragma unroll
  for (int i = 0; i < 4; ++i) {
    int ch = i * 64 + lane;
    int r = ch >> 2, qo = (ch & 3) * 8;
    *(short8*)&qs[r * 40 + qo] = *(const short8*)&qg[r * 32 + qo];
    *(short8*)&ks[r * 40 + qo] = *(const short8*)&kg[r * 32 + qo];
  }
  {
    short8 v0 = *(const short8*)&vg[(size_t)lane * 32];
    short8 v1 = *(const short8*)&vg[(size_t)lane * 32 + 8];
    short8 v2 = *(const short8*)&vg[(size_t)lane * 32 + 16];
    short8 v3 = *(const short8*)&vg[(size_t)lane * 32 + 24];
#pragma unroll
    for (int j = 0; j < 8; ++j) {
      vt[j * 72 + lane] = (u16)v0[j];
      vt[(8 + j) * 72 + lane] = (u16)v1[j];
      vt[(16 + j) * 72 + lane] = (u16)v2[j];
      vt[(24 + j) * 72 + lane] = (u16)v3[j];
    }
  }
  __syncthreads();
  f32x4 sf[4][4];
#pragma unroll
  for (int mi = 0; mi < 4; ++mi)
#pragma unroll
    for (int ni = 0; ni < 4; ++ni) sf[mi][ni] = (f32x4){0.f, 0.f, 0.f, 0.f};
  {
    short8 a[4], bq[4];
#pragma unroll
    for (int mi = 0; mi < 4; ++mi) a[mi] = *(const short8*)&qs[(mi * 16 + lr) * 40 + lg * 8];
#pragma unroll
    for (int ni = 0; ni < 4; ++ni) bq[ni] = *(const short8*)&ks[(ni * 16 + lr) * 40 + lg * 8];
#pragma unroll
    for (int mi = 0; mi < 4; ++mi)
#pragma unroll
      for (int ni = 0; ni < 4; ++ni) sf[mi][ni] = MFMA16(a[mi], bq[ni], sf[mi][ni]);
  }
  const float* bh = biasf + (size_t)head * 4096;
#pragma unroll
  for (int mi = 0; mi < 4; ++mi) {
#pragma unroll
    for (int r = 0; r < 4; ++r) {
      const int n = mi * 16 + lg * 4 + r;
      float v0 = sf[mi][0][r] + bh[n * 64 + lr];
      float v1 = sf[mi][1][r] + bh[n * 64 + 16 + lr];
      float v2 = sf[mi][2][r] + bh[n * 64 + 32 + lr];
      float v3 = sf[mi][3][r] + bh[n * 64 + 48 + lr];
      float mx = fmaxf(fmaxf(v0, v1), fmaxf(v2, v3));
      mx = fmaxf(mx, __shfl_xor(mx, 1));
      mx = fmaxf(mx, __shfl_xor(mx, 2));
      mx = fmaxf(mx, __shfl_xor(mx, 4));
      mx = fmaxf(mx, __shfl_xor(mx, 8));
      float e0 = __expf(v0 - mx), e1 = __expf(v1 - mx);
      float e2 = __expf(v2 - mx), e3 = __expf(v3 - mx);
      float sm = e0 + e1 + e2 + e3;
      sm += __shfl_xor(sm, 1);
      sm += __shfl_xor(sm, 2);
      sm += __shfl_xor(sm, 4);
      sm += __shfl_xor(sm, 8);
      const float inv = 1.f / sm;
      pp[n * 72 + lr] = f2b(e0 * inv);
      pp[n * 72 + 16 + lr] = f2b(e1 * inv);
      pp[n * 72 + 32 + lr] = f2b(e2 * inv);
      pp[n * 72 + 48 + lr] = f2b(e3 * inv);
    }
  }
  __syncthreads();
  f32x4 o[4][2];
#pragma unroll
  for (int mi = 0; mi < 4; ++mi)
#pragma unroll
    for (int ni = 0; ni < 2; ++ni) o[mi][ni] = (f32x4){0.f, 0.f, 0.f, 0.f};
#pragma unroll
  for (int kk = 0; kk < 2; ++kk) {
    short8 pa[4], vb[2];
#pragma unroll
    for (int mi = 0; mi < 4; ++mi)
      pa[mi] = *(const short8*)&pp[(mi * 16 + lr) * 72 + kk * 32 + lg * 8];
#pragma unroll
    for (int ni = 0; ni < 2; ++ni)
      vb[ni] = *(const short8*)&vt[(ni * 16 + lr) * 72 + kk * 32 + lg * 8];
#pragma unroll
    for (int mi = 0; mi < 4; ++mi)
#pragma unroll
      for (int ni = 0; ni < 2; ++ni) o[mi][ni] = MFMA16(pa[mi], vb[ni], o[mi][ni]);
  }
  u16* op = aout + (size_t)win * 16384 + head * 32;
#pragma unroll
  for (int mi = 0; mi < 4; ++mi)
#pragma unroll
    for (int ni = 0; ni < 2; ++ni)
#pragma unroll
      for (int r = 0; r < 4; ++r) {
        const int n = mi * 16 + lg * 4 + r;
        op[(size_t)n * 256 + ni * 16 + lr] = f2b(o[mi][ni][r]);
      }
}

// ---------------- K5: LN2, one wave per row ----------------
__global__ __launch_bounds__(256) void ln2_kernel(const float* __restrict__ xs2,
                                                  const float* __restrict__ g,
                                                  const float* __restrict__ b,
                                                  u16* __restrict__ h2) {
  const int wv = threadIdx.x >> 6, lane = threadIdx.x & 63;
  const size_t row = (size_t)blockIdx.x * 4 + wv;
  const f32x4 xv = *(const f32x4*)&xs2[row * 256 + lane * 4];
  float s = xv[0] + xv[1] + xv[2] + xv[3];
  float q = xv[0] * xv[0] + xv[1] * xv[1] + xv[2] * xv[2] + xv[3] * xv[3];
#pragma unroll
  for (int off = 1; off < 64; off <<= 1) {
    s += __shfl_xor(s, off);
    q += __shfl_xor(q, off);
  }
  const float m = s * (1.f / 256.f);
  const float rstd = rsqrtf(q * (1.f / 256.f) - m * m + 1e-5f);
  const f32x4 gv = *(const f32x4*)&g[lane * 4];
  const f32x4 bv = *(const f32x4*)&b[lane * 4];
  union {
    u16 u[4];
    unsigned long long v;
  } pk;
#pragma unroll
  for (int j = 0; j < 4; ++j) pk.u[j] = f2b((xv[j] - m) * rstd * gv[j] + bv[j]);
  *(unsigned long long*)&h2[row * 256 + lane * 4] = pk.v;
}

extern "C" void kernel_launch(void* const* d_in, const int* in_sizes, int n_in,
                              void* d_out, int out_size, void* d_ws, size_t ws_size,
                              hipStream_t stream) {
  const float* x = (const float*)d_in[0];
  const float* n1g = (const float*)d_in[1];
  const float* n1b = (const float*)d_in[2];
  const float* qkv_w = (const float*)d_in[3];
  const float* qkv_b = (const float*)d_in[4];
  const float* tbl = (const float*)d_in[5];
  const float* proj_w = (const float*)d_in[6];
  const float* proj_b = (const float*)d_in[7];
  const float* n2g = (const float*)d_in[8];
  const float* n2b = (const float*)d_in[9];
  const float* fc1_w = (const float*)d_in[10];
  const float* fc1_b = (const float*)d_in[11];
  const float* fc2_w = (const float*)d_in[12];
  const float* fc2_b = (const float*)d_in[13];
  const int* relidx = (const int*)d_in[14];
  float* outp = (float*)d_out;

  char* w = (char*)d_ws;
  const size_t Mi = 1ull << 20;
  if (ws_size < 237 * Mi) return;
  u16* Y = (u16*)(w + 0);
  u16* qb = (u16*)(w + 32 * Mi);
  u16* aout = (u16*)(w + 0);
  float* xs2 = (float*)(w + 32 * Mi);
  u16* h2 = (u16*)(w + 0);
  u16* h1 = (u16*)(w + 96 * Mi);
  u16* wqkv = (u16*)(w + 224 * Mi);
  u16* wproj = wqkv + 196608;
  u16* wfc1 = wproj + 65536;
  u16* wfc2 = wfc1 + 262144;
  float* bfull = (float*)(w + 224 * Mi + 1572864);

  f2bf_kernel<<<768, 256, 0, stream>>>(qkv_w, wqkv, 196608);
  f2bf_kernel<<<256, 256, 0, stream>>>(proj_w, wproj, 65536);
  f2bf_kernel<<<1024, 256, 0, stream>>>(fc1_w, wfc1, 262144);
  f2bf_kernel<<<1024, 256, 0, stream>>>(fc2_w, wfc2, 262144);
  biasfull_kernel<<<128, 256, 0, stream>>>(tbl, relidx, bfull);

  ln1_win_kernel<<<1024, 256, 0, stream>>>(x, n1g, n1b, Y);
  gemm_pers<0, 12, 8, 768><<<768, 256, 0, stream>>>(Y, wqkv, qkv_b, qb, nullptr, nullptr);
  attn_kernel<<<8192, 64, 0, stream>>>(qb, bfull, aout);
  gemm_pers<1, 4, 4, 256><<<512, 256, 0, stream>>>(aout, wproj, proj_b, nullptr, xs2, x);
  ln2_kernel<<<16384, 256, 0, stream>>>(xs2, n2g, n2b, h2);
  gemm_pers<2, 16, 8, 1024><<<1024, 256, 0, stream>>>(h2, wfc1, fc1_b, h1, nullptr, nullptr);
  gemm_fc2<<<1024, 256, 0, stream>>>(h1, wfc2, fc2_b, outp, xs2);
}

// Round 4
// 300.081 us; speedup vs baseline: 1.3354x; 1.3354x over previous
//
#include <hip/hip_runtime.h>

typedef unsigned short u16;
typedef __attribute__((ext_vector_type(8))) short short8;
typedef __attribute__((ext_vector_type(4))) float f32x4;

#define MFMA16(a, b, c) __builtin_amdgcn_mfma_f32_16x16x32_bf16((a), (b), (c), 0, 0, 0)
#define WAITV(N) asm volatile("s_waitcnt vmcnt(" #N ")" ::: "memory")
#define BARS() __builtin_amdgcn_s_barrier()
#define MFENCE() asm volatile("" ::: "memory")

__device__ __forceinline__ u16 f2b(float f) {
  unsigned b = __float_as_uint(f);
  b += 0x7FFFu + ((b >> 16) & 1u);
  return (u16)(b >> 16);
}

__device__ __forceinline__ void gload_lds16(const void* g, void* l) {
  __builtin_amdgcn_global_load_lds((const __attribute__((address_space(1))) void*)g,
                                   (__attribute__((address_space(3))) void*)l, 16, 0, 0);
}

// fast exact-enough GELU: erf via Abramowitz-Stegun 7.1.26 (|err|<=1.5e-7)
__device__ __forceinline__ float fast_gelu(float x) {
  const float u = x * 0.70710678118654752f;
  const float au = fabsf(u);
  float d = 1.f + 0.3275911f * au;
  float tt;
  asm("v_rcp_f32 %0, %1" : "=v"(tt) : "v"(d));
  float p = 1.061405429f * tt - 1.453152027f;
  p = p * tt + 1.421413741f;
  p = p * tt - 0.284496736f;
  p = p * tt + 0.254829592f;
  p = p * tt;
  const float e = __expf(-u * u);
  const float erf_au = 1.f - p * e;
  return 0.5f * x * (1.f + copysignf(erf_au, x));
}

// ---------------- merged setup: weight f32->bf16 + bias table expand ----------------
__global__ __launch_bounds__(256) void prep_kernel(
    const float* __restrict__ qkv_w, const float* __restrict__ proj_w,
    const float* __restrict__ fc1_w, const float* __restrict__ fc2_w,
    const float* __restrict__ tbl, const int* __restrict__ ridx,
    u16* __restrict__ wqkv, u16* __restrict__ wproj, u16* __restrict__ wfc1,
    u16* __restrict__ wfc2, float* __restrict__ bfull) {
  int i = blockIdx.x * 256 + threadIdx.x;
  if (i < 196608) {
    wqkv[i] = f2b(qkv_w[i]);
  } else if (i < 262144) {
    wproj[i - 196608] = f2b(proj_w[i - 196608]);
  } else if (i < 524288) {
    wfc1[i - 262144] = f2b(fc1_w[i - 262144]);
  } else if (i < 786432) {
    wfc2[i - 524288] = f2b(fc2_w[i - 524288]);
  } else {
    int j = i - 786432;  // j < 32768
    int hm = j >> 12, nm = j & 4095;
    bfull[j] = tbl[ridx[nm] * 8 + hm];
  }
}

// ---------------- K1: LN1 + window partition -> Y bf16 [65536][256] ----------------
__global__ __launch_bounds__(256) void ln1_win_kernel(const float* __restrict__ x,
                                                      const float* __restrict__ g,
                                                      const float* __restrict__ b,
                                                      u16* __restrict__ y) {
  __shared__ float red[2][4][64];
  const int bh = blockIdx.x;  // b*64 + h
  const int bb = bh >> 6, h = bh & 63;
  const int w = threadIdx.x & 63, cg = threadIdx.x >> 6;
  const float* xp = x + (size_t)bb * 1048576 + (size_t)h * 64 + w;
  float vals[64];
  float s = 0.f, ss = 0.f;
#pragma unroll
  for (int j = 0; j < 64; ++j) {
    float v = xp[(size_t)(cg * 64 + j) * 4096];
    vals[j] = v;
    s += v;
    ss += v * v;
  }
  red[0][cg][w] = s;
  red[1][cg][w] = ss;
  __syncthreads();
  const float S = red[0][0][w] + red[0][1][w] + red[0][2][w] + red[0][3][w];
  const float Q = red[1][0][w] + red[1][1][w] + red[1][2][w] + red[1][3][w];
  const float m = S * (1.f / 256.f);
  const float rstd = rsqrtf(Q * (1.f / 256.f) - m * m + 1e-5f);
  const int win = bb * 64 + ((h >> 3) << 3) + (w >> 3);
  const int tok = ((h & 7) << 3) + (w & 7);
  u16* yp = y + (size_t)win * 16384 + tok * 256 + cg * 64;
#pragma unroll
  for (int jj = 0; jj < 8; ++jj) {
    short8 o;
#pragma unroll
    for (int q = 0; q < 8; ++q) {
      const int c64 = jj * 8 + q;
      const int c = cg * 64 + c64;
      o[q] = (short)f2b((vals[c64] - m) * rstd * g[c] + b[c]);
    }
    *(short8*)&yp[jj * 8] = o;
  }
}

// ---------------- GEMM: out = A[65536 x KT] * W[NC x KT]^T + bias, bf16 MFMA ----------
// 128x128 tile, BK=64, double-buffered with counted vmcnt (never drain mid-loop).
// XCD-chunked work remap: xcd owns contiguous mt range, nt innermost -> A-panel's
// NNT sharers are consecutive blocks on ONE XCD (L2-hot); W slice stays L2-resident.
// EPI 0: qkv scatter (+q scale).  1: proj + x residual -> xs2 fp32.
// EPI 2: fc1 + fast GELU -> bf16. 3: fc2 + xs2 residual -> d_out BCHW fp32.
template <int EPI, int KT, int NNT>
__global__ __launch_bounds__(256, 2) void gemm_bt(const u16* __restrict__ A,
                                                  const u16* __restrict__ W,
                                                  const float* __restrict__ bias,
                                                  u16* __restrict__ outh,
                                                  float* __restrict__ outf,
                                                  const float* __restrict__ aux) {
  constexpr int NTK = KT >> 6;
  constexpr int NC = NNT * 128;
  __shared__ __align__(16) u16 As[2][8192];
  __shared__ __align__(16) u16 Bs[2][8192];
  const int xcd = blockIdx.x & 7, ii = blockIdx.x >> 3;
  const int mt = xcd * 64 + ii / NNT;  // grid = 512*NNT, 512 m-tiles, 64 per XCD
  const int nt = ii % NNT;
  const int tid = threadIdx.x;
  const int wv = tid >> 6, lane = tid & 63;
  const int wr = (wv >> 1) << 6;  // wave row quadrant
  const int wc = (wv & 1) << 6;   // wave col quadrant
  const int lrow = lane >> 3;
  const int lkswz = (((lane & 7) ^ lrow) << 3);  // swizzled source k-offset
  const int lr = lane & 15, lg = lane >> 4;
  const int swz = (lr & 7) << 3;  // read-side XOR
  f32x4 acc[4][4];
#pragma unroll
  for (int mi = 0; mi < 4; ++mi)
#pragma unroll
    for (int ni = 0; ni < 4; ++ni) acc[mi][ni] = (f32x4){0.f, 0.f, 0.f, 0.f};
  const u16* Ab = A + (size_t)mt * 128 * KT;
  const u16* Wb = W + (size_t)nt * 128 * KT;

#define STG(BF, T)                                                                      \
  {                                                                                     \
    const int kt_ = (T) << 6;                                                           \
    _Pragma("unroll") for (int i_ = 0; i_ < 4; ++i_) {                                  \
      const int rb_ = wv * 32 + i_ * 8;                                                 \
      gload_lds16(Ab + (size_t)(rb_ + lrow) * KT + kt_ + lkswz, &As[BF][rb_ * 64]);     \
    }                                                                                   \
    _Pragma("unroll") for (int i_ = 0; i_ < 4; ++i_) {                                  \
      const int rb_ = wv * 32 + i_ * 8;                                                 \
      gload_lds16(Wb + (size_t)(rb_ + lrow) * KT + kt_ + lkswz, &Bs[BF][rb_ * 64]);     \
    }                                                                                   \
  }
#define CMPT(BF)                                                                        \
  {                                                                                     \
    _Pragma("unroll") for (int kk = 0; kk < 2; ++kk) {                                  \
      const int kq = (kk * 32 + lg * 8) ^ swz;                                          \
      short8 a_[4], b_[4];                                                              \
      _Pragma("unroll") for (int mi = 0; mi < 4; ++mi)                                  \
          a_[mi] = *(const short8*)&As[BF][(wr + mi * 16 + lr) * 64 + kq];              \
      _Pragma("unroll") for (int ni = 0; ni < 4; ++ni)                                  \
          b_[ni] = *(const short8*)&Bs[BF][(wc + ni * 16 + lr) * 64 + kq];              \
      _Pragma("unroll") for (int mi = 0; mi < 4; ++mi)                                  \
          _Pragma("unroll") for (int ni = 0; ni < 4; ++ni)                              \
              acc[mi][ni] = MFMA16(a_[mi], b_[ni], acc[mi][ni]);                        \
    }                                                                                   \
  }

  STG(0, 0);
  STG(1, 1);
#pragma unroll
  for (int t = 0; t < NTK; ++t) {
    if (t + 1 < NTK) {
      WAITV(8);  // own tile-t loads done; t+1's 8 stay in flight
    } else {
      WAITV(0);
    }
    BARS();
    MFENCE();
    CMPT(t & 1);
    MFENCE();
    BARS();  // all waves done reading buffer (t&1) before overwrite
    if (t + 2 < NTK) STG(t & 1, t + 2);
  }
#undef STG
#undef CMPT

  const int row0 = mt * 128 + wr + lg * 4;  // + mi*16 + r
  const int col0 = nt * 128 + wc + lr;      // + ni*16

  if constexpr (EPI == 0) {
    // scatter into q/k/v [win][head][64][32]; q scaled by 32^-0.5
#pragma unroll
    for (int mi = 0; mi < 4; ++mi)
#pragma unroll
      for (int ni = 0; ni < 4; ++ni) {
        const int col = col0 + ni * 16;
        const int which = col >> 8, cc = col & 255;
        const int head = cc >> 5, hd = cc & 31;
        u16* dst = outh + (size_t)which * 16777216ull;
        const float scl = (which == 0) ? 0.17677669529663689f : 1.0f;
        const float bv = bias[col];
#pragma unroll
        for (int r = 0; r < 4; ++r) {
          const int row = row0 + mi * 16 + r;
          const int win = row >> 6, tk = row & 63;
          dst[(((size_t)(win * 8 + head) << 6) + tk) * 32 + hd] =
              f2b((acc[mi][ni][r] + bv) * scl);
        }
      }
  } else if constexpr (EPI == 1) {
#pragma unroll
    for (int mi = 0; mi < 4; ++mi)
#pragma unroll
      for (int ni = 0; ni < 4; ++ni) {
        const int col = col0 + ni * 16;
        const float bv = bias[col];
#pragma unroll
        for (int r = 0; r < 4; ++r) {
          const int row = row0 + mi * 16 + r;
          const int win = row >> 6, tk = row & 63;
          const int bb = win >> 6;
          const int h = (((win >> 3) & 7) << 3) + (tk >> 3);
          const int w = ((win & 7) << 3) + (tk & 7);
          float val = acc[mi][ni][r] + bv +
                      aux[(((size_t)bb * 256 + col) * 64 + h) * 64 + w];
          outf[(size_t)row * 256 + col] = val;
        }
      }
  } else if constexpr (EPI == 2) {
#pragma unroll
    for (int mi = 0; mi < 4; ++mi)
#pragma unroll
      for (int ni = 0; ni < 4; ++ni) {
        const int col = col0 + ni * 16;
        const float bv = bias[col];
#pragma unroll
        for (int r = 0; r < 4; ++r) {
          const int row = row0 + mi * 16 + r;
          outh[(size_t)row * NC + col] = f2b(fast_gelu(acc[mi][ni][r] + bv));
        }
      }
  } else {  // EPI == 3
#pragma unroll
    for (int mi = 0; mi < 4; ++mi)
#pragma unroll
      for (int ni = 0; ni < 4; ++ni) {
        const int col = col0 + ni * 16;
        const float bv = bias[col];
        const int row = row0 + mi * 16;  // rows row..row+3 are 4 consecutive w
        const int win = row >> 6, tk = row & 63;
        const int bb = win >> 6;
        const int h = (((win >> 3) & 7) << 3) + (tk >> 3);
        const int w = ((win & 7) << 3) + (tk & 7);
        f32x4 v;
#pragma unroll
        for (int r = 0; r < 4; ++r)
          v[r] = acc[mi][ni][r] + bv + aux[(size_t)(row + r) * 256 + col];
        *(f32x4*)&outf[(((size_t)bb * 256 + col) * 64 + h) * 64 + w] = v;
      }
  }
}

// ---------------- K3: windowed attention, 1 wave per (window, head) ----------------
// LDS overlay: pp reuses qs/ks region after QK^T (14.5 KB total -> ~10 blocks/CU)
__global__ __launch_bounds__(64) void attn_kernel(const u16* __restrict__ qkv,
                                                  const float* __restrict__ biasf,
                                                  u16* __restrict__ aout) {
  __shared__ __align__(16) u16 sqk[5120];  // qs[0,2560) ks[2560,5120); pp overlays [0,4608)
  __shared__ __align__(16) u16 vt[2304];   // v transposed [hd][m], stride 72
  u16* qs = sqk;
  u16* ks = sqk + 2560;
  u16* pp = sqk;
  const int wh = blockIdx.x;
  const int head = wh & 7;
  const int win = wh >> 3;
  const int lane = threadIdx.x;
  const int lr = lane & 15, lg = lane >> 4;
  const u16* qg = qkv + (size_t)wh * 2048;
  const u16* kg = qkv + 16777216ull + (size_t)wh * 2048;
  const u16* vg = qkv + 33554432ull + (size_t)wh * 2048;
#pragma unroll
  for (int i = 0; i < 4; ++i) {
    int ch = i * 64 + lane;
    int r = ch >> 2, qo = (ch & 3) * 8;
    *(short8*)&qs[r * 40 + qo] = *(const short8*)&qg[r * 32 + qo];
    *(short8*)&ks[r * 40 + qo] = *(const short8*)&kg[r * 32 + qo];
  }
  {
    short8 v0 = *(const short8*)&vg[(size_t)lane * 32];
    short8 v1 = *(const short8*)&vg[(size_t)lane * 32 + 8];
    short8 v2 = *(const short8*)&vg[(size_t)lane * 32 + 16];
    short8 v3 = *(const short8*)&vg[(size_t)lane * 32 + 24];
#pragma unroll
    for (int j = 0; j < 8; ++j) {
      vt[j * 72 + lane] = (u16)v0[j];
      vt[(8 + j) * 72 + lane] = (u16)v1[j];
      vt[(16 + j) * 72 + lane] = (u16)v2[j];
      vt[(24 + j) * 72 + lane] = (u16)v3[j];
    }
  }
  __syncthreads();
  f32x4 sf[4][4];
#pragma unroll
  for (int mi = 0; mi < 4; ++mi)
#pragma unroll
    for (int ni = 0; ni < 4; ++ni) sf[mi][ni] = (f32x4){0.f, 0.f, 0.f, 0.f};
  {
    short8 a[4], bq[4];
#pragma unroll
    for (int mi = 0; mi < 4; ++mi) a[mi] = *(const short8*)&qs[(mi * 16 + lr) * 40 + lg * 8];
#pragma unroll
    for (int ni = 0; ni < 4; ++ni) bq[ni] = *(const short8*)&ks[(ni * 16 + lr) * 40 + lg * 8];
#pragma unroll
    for (int mi = 0; mi < 4; ++mi)
#pragma unroll
      for (int ni = 0; ni < 4; ++ni) sf[mi][ni] = MFMA16(a[mi], bq[ni], sf[mi][ni]);
  }
  __syncthreads();  // qs/ks frag reads retired before pp overlay writes
  const float* bh = biasf + (size_t)head * 4096;
#pragma unroll
  for (int mi = 0; mi < 4; ++mi) {
#pragma unroll
    for (int r = 0; r < 4; ++r) {
      const int n = mi * 16 + lg * 4 + r;
      float v0 = sf[mi][0][r] + bh[n * 64 + lr];
      float v1 = sf[mi][1][r] + bh[n * 64 + 16 + lr];
      float v2 = sf[mi][2][r] + bh[n * 64 + 32 + lr];
      float v3 = sf[mi][3][r] + bh[n * 64 + 48 + lr];
      float mx = fmaxf(fmaxf(v0, v1), fmaxf(v2, v3));
      mx = fmaxf(mx, __shfl_xor(mx, 1));
      mx = fmaxf(mx, __shfl_xor(mx, 2));
      mx = fmaxf(mx, __shfl_xor(mx, 4));
      mx = fmaxf(mx, __shfl_xor(mx, 8));
      float e0 = __expf(v0 - mx), e1 = __expf(v1 - mx);
      float e2 = __expf(v2 - mx), e3 = __expf(v3 - mx);
      float sm = e0 + e1 + e2 + e3;
      sm += __shfl_xor(sm, 1);
      sm += __shfl_xor(sm, 2);
      sm += __shfl_xor(sm, 4);
      sm += __shfl_xor(sm, 8);
      const float inv = 1.f / sm;
      pp[n * 72 + lr] = f2b(e0 * inv);
      pp[n * 72 + 16 + lr] = f2b(e1 * inv);
      pp[n * 72 + 32 + lr] = f2b(e2 * inv);
      pp[n * 72 + 48 + lr] = f2b(e3 * inv);
    }
  }
  __syncthreads();
  f32x4 o[4][2];
#pragma unroll
  for (int mi = 0; mi < 4; ++mi)
#pragma unroll
    for (int ni = 0; ni < 2; ++ni) o[mi][ni] = (f32x4){0.f, 0.f, 0.f, 0.f};
#pragma unroll
  for (int kk = 0; kk < 2; ++kk) {
    short8 pa[4], vb[2];
#pragma unroll
    for (int mi = 0; mi < 4; ++mi)
      pa[mi] = *(const short8*)&pp[(mi * 16 + lr) * 72 + kk * 32 + lg * 8];
#pragma unroll
    for (int ni = 0; ni < 2; ++ni)
      vb[ni] = *(const short8*)&vt[(ni * 16 + lr) * 72 + kk * 32 + lg * 8];
#pragma unroll
    for (int mi = 0; mi < 4; ++mi)
#pragma unroll
      for (int ni = 0; ni < 2; ++ni) o[mi][ni] = MFMA16(pa[mi], vb[ni], o[mi][ni]);
  }
  u16* op = aout + (size_t)win * 16384 + head * 32;
#pragma unroll
  for (int mi = 0; mi < 4; ++mi)
#pragma unroll
    for (int ni = 0; ni < 2; ++ni)
#pragma unroll
      for (int r = 0; r < 4; ++r) {
        const int n = mi * 16 + lg * 4 + r;
        op[(size_t)n * 256 + ni * 16 + lr] = f2b(o[mi][ni][r]);
      }
}

// ---------------- K5: LN2, one wave per row ----------------
__global__ __launch_bounds__(256) void ln2_kernel(const float* __restrict__ xs2,
                                                  const float* __restrict__ g,
                                                  const float* __restrict__ b,
                                                  u16* __restrict__ h2) {
  const int wv = threadIdx.x >> 6, lane = threadIdx.x & 63;
  const size_t row = (size_t)blockIdx.x * 4 + wv;
  const f32x4 xv = *(const f32x4*)&xs2[row * 256 + lane * 4];
  float s = xv[0] + xv[1] + xv[2] + xv[3];
  float q = xv[0] * xv[0] + xv[1] * xv[1] + xv[2] * xv[2] + xv[3] * xv[3];
#pragma unroll
  for (int off = 1; off < 64; off <<= 1) {
    s += __shfl_xor(s, off);
    q += __shfl_xor(q, off);
  }
  const float m = s * (1.f / 256.f);
  const float rstd = rsqrtf(q * (1.f / 256.f) - m * m + 1e-5f);
  const f32x4 gv = *(const f32x4*)&g[lane * 4];
  const f32x4 bv = *(const f32x4*)&b[lane * 4];
  union {
    u16 u[4];
    unsigned long long v;
  } pk;
#pragma unroll
  for (int j = 0; j < 4; ++j) pk.u[j] = f2b((xv[j] - m) * rstd * gv[j] + bv[j]);
  *(unsigned long long*)&h2[row * 256 + lane * 4] = pk.v;
}

extern "C" void kernel_launch(void* const* d_in, const int* in_sizes, int n_in,
                              void* d_out, int out_size, void* d_ws, size_t ws_size,
                              hipStream_t stream) {
  const float* x = (const float*)d_in[0];
  const float* n1g = (const float*)d_in[1];
  const float* n1b = (const float*)d_in[2];
  const float* qkv_w = (const float*)d_in[3];
  const float* qkv_b = (const float*)d_in[4];
  const float* tbl = (const float*)d_in[5];
  const float* proj_w = (const float*)d_in[6];
  const float* proj_b = (const float*)d_in[7];
  const float* n2g = (const float*)d_in[8];
  const float* n2b = (const float*)d_in[9];
  const float* fc1_w = (const float*)d_in[10];
  const float* fc1_b = (const float*)d_in[11];
  const float* fc2_w = (const float*)d_in[12];
  const float* fc2_b = (const float*)d_in[13];
  const int* relidx = (const int*)d_in[14];
  float* outp = (float*)d_out;

  char* w = (char*)d_ws;
  const size_t Mi = 1ull << 20;
  // ws timeline (reuse): [0,32Mi): Y -> attn_out -> h2 ; [32,96Mi): q,k -> xs2 ;
  // [96,224Mi): v (first 32Mi) -> h1 ; [224Mi..): bf16 weights + bias table.
  if (ws_size < 237 * Mi) return;
  u16* Y = (u16*)(w + 0);
  u16* qb = (u16*)(w + 32 * Mi);
  u16* aout = (u16*)(w + 0);
  float* xs2 = (float*)(w + 32 * Mi);
  u16* h2 = (u16*)(w + 0);
  u16* h1 = (u16*)(w + 96 * Mi);
  u16* wqkv = (u16*)(w + 224 * Mi);
  u16* wproj = wqkv + 196608;
  u16* wfc1 = wproj + 65536;
  u16* wfc2 = wfc1 + 262144;
  float* bfull = (float*)(w + 224 * Mi + 1572864);

  prep_kernel<<<3200, 256, 0, stream>>>(qkv_w, proj_w, fc1_w, fc2_w, tbl, relidx, wqkv,
                                        wproj, wfc1, wfc2, bfull);
  ln1_win_kernel<<<1024, 256, 0, stream>>>(x, n1g, n1b, Y);
  gemm_bt<0, 256, 6><<<3072, 256, 0, stream>>>(Y, wqkv, qkv_b, qb, nullptr, nullptr);
  attn_kernel<<<8192, 64, 0, stream>>>(qb, bfull, aout);
  gemm_bt<1, 256, 2><<<1024, 256, 0, stream>>>(aout, wproj, proj_b, nullptr, xs2, x);
  ln2_kernel<<<16384, 256, 0, stream>>>(xs2, n2g, n2b, h2);
  gemm_bt<2, 256, 8><<<4096, 256, 0, stream>>>(h2, wfc1, fc1_b, h1, nullptr, nullptr);
  gemm_bt<3, 1024, 2><<<1024, 256, 0, stream>>>(h1, wfc2, fc2_b, nullptr, outp, xs2);
}